// Round 6
// baseline (128.657 us; speedup 1.0000x reference)
//
#include <hip/hip_runtime.h>

#define EPS 1e-5f

typedef float f4 __attribute__((ext_vector_type(4)));

// ws layout (floats):
//  fz    : [0      , 8192  )   [16][512]
//  featx : [8192   , 73728 )   [16][256][16]  (mean over H)
//  featy : [73728  , 139264)   [16][256][16]  (mean over W)
//  imgz  : [139264 , 401408)   [16][16384]    (= [16][256][64])
#define WS_FZ    0
#define WS_FX    8192
#define WS_FY    73728
#define WS_IMGZ  139264

// ---------------------------------------------------------------------------
// k1: fz = mean(img_feat, HW) ; feat_x = mean(encoding, H) ; feat_y = mean(encoding, W)
// (R2 version, unchanged)
// ---------------------------------------------------------------------------
__global__ __launch_bounds__(256) void k1_reduce(const float* __restrict__ img_feat,
                                                 const float* __restrict__ encoding,
                                                 float* __restrict__ ws) {
    int bid = blockIdx.x;
    if (bid < 2048) {
        int wave = (bid * 256 + (int)threadIdx.x) >> 6;   // 0..8191  (b*512+c)
        int lane = threadIdx.x & 63;
        const f4* src = reinterpret_cast<const f4*>(img_feat + (size_t)wave * 256);
        f4 v = src[lane];
        float s = v.x + v.y + v.z + v.w;
        #pragma unroll
        for (int m = 32; m >= 1; m >>= 1) s += __shfl_xor(s, m, 64);
        if (lane == 0) ws[WS_FZ + wave] = s * (1.0f / 256.0f);
    } else {
        int t = (bid - 2048) * 256 + (int)threadIdx.x;    // 0..131071
        if (t < 65536) {
            // feat_x: t = bc*16 + w ; mean over h (stride 16)
            int w  = t & 15;
            int bc = t >> 4;
            const float* src = encoding + (size_t)bc * 256 + w;
            float s = 0.f;
            #pragma unroll
            for (int h = 0; h < 16; ++h) s += src[h * 16];
            ws[WS_FX + t] = s * (1.0f / 16.0f);
        } else {
            // feat_y: u = bc*16 + h ; mean over w (contiguous 16)
            int u  = t - 65536;
            int h  = u & 15;
            int bc = u >> 4;
            const f4* src = reinterpret_cast<const f4*>(encoding + (size_t)bc * 256 + h * 16);
            f4 a = src[0], b = src[1], c = src[2], d = src[3];
            float s = (a.x + a.y + a.z + a.w) + (b.x + b.y + b.z + b.w)
                    + (c.x + c.y + c.z + c.w) + (d.x + d.y + d.z + d.w);
            ws[WS_FY + u] = s * (1.0f / 16.0f);
        }
    }
}

// ---------------------------------------------------------------------------
// k2: imgz[b][o] = relu(BN(wz1[o,:]·fz[b,:] + bz1[o]))  (R2 version, unchanged)
// ---------------------------------------------------------------------------
__global__ __launch_bounds__(256) void k2_zmlp(const float* __restrict__ wz1,
                                               const float* __restrict__ bz1,
                                               const float* __restrict__ gamma,
                                               const float* __restrict__ beta,
                                               const float* __restrict__ rmean,
                                               const float* __restrict__ rvar,
                                               float* __restrict__ ws) {
    __shared__ float fzl[16][516];   // +4 pad: ds_read_b128 lane banks 4*(b+i)%32 -> 2-way
    int tid = threadIdx.x;
    #pragma unroll
    for (int i = 0; i < 32; ++i) {
        int idx = i * 256 + tid;          // 0..8191
        fzl[idx >> 9][idx & 511] = ws[WS_FZ + idx];
    }
    __syncthreads();

    int o    = (blockIdx.x * 256 + tid) >> 6;  // 0..16383
    int lane = tid & 63;
    int b    = lane & 15;
    int kg   = lane >> 4;                      // 0..3 (128 k's each)
    const f4* wrow = reinterpret_cast<const f4*>(wz1 + (size_t)o * 512 + kg * 128);
    const f4* fr   = reinterpret_cast<const f4*>(&fzl[b][kg * 128]);
    float acc = 0.f;
    #pragma unroll
    for (int i = 0; i < 32; ++i) {
        f4 wv = wrow[i];
        f4 fv = fr[i];
        acc = fmaf(wv.x, fv.x, acc);
        acc = fmaf(wv.y, fv.y, acc);
        acc = fmaf(wv.z, fv.z, acc);
        acc = fmaf(wv.w, fv.w, acc);
    }
    acc += __shfl_xor(acc, 16, 64);
    acc += __shfl_xor(acc, 32, 64);
    if (lane < 16) {
        float z = acc + bz1[o];
        z = gamma[o] * (z - rmean[o]) * rsqrtf(rvar[o] + EPS) + beta[o];
        z = fmaxf(z, 0.f);
        ws[WS_IMGZ + (size_t)b * 16384 + o] = z;
    }
}

// ---------------------------------------------------------------------------
// k3: joint coords. One 128-thread block per (b,j). (R2 version, unchanged)
// ---------------------------------------------------------------------------
__global__ __launch_bounds__(128) void k3_coords(const float* __restrict__ wx,
                                                 const float* __restrict__ bx,
                                                 const float* __restrict__ wy,
                                                 const float* __restrict__ by,
                                                 const float* __restrict__ wz2,
                                                 const float* __restrict__ bz2,
                                                 const float* __restrict__ ws,
                                                 float* __restrict__ out_coord) {
    int bidx = blockIdx.x;
    int b = bidx / 21;
    int j = bidx - b * 21;
    int tid  = threadIdx.x;
    float* oj = out_coord + (size_t)b * 63 + j * 3;

    if (tid < 64) {
        int lane = tid;
        const float* imgz = ws + WS_IMGZ + (size_t)b * 16384;
        const float* wr   = wz2 + j * 256;
        float hz = bz2[j];
        #pragma unroll 8
        for (int c = 0; c < 256; ++c)
            hz = fmaf(wr[c], imgz[c * 64 + lane], hz);

        float m = hz;
        #pragma unroll
        for (int mk = 32; mk >= 1; mk >>= 1) m = fmaxf(m, __shfl_xor(m, mk, 64));
        float e = expf(hz - m);
        float s = e;
        float n = e * (float)lane;
        #pragma unroll
        for (int mk = 32; mk >= 1; mk >>= 1) {
            s += __shfl_xor(s, mk, 64);
            n += __shfl_xor(n, mk, 64);
        }
        if (lane == 0) oj[2] = n / s;
    } else if (tid < 96) {
        int lane = tid - 64;
        int w = lane & 15;
        const float* feat = (lane < 16) ? (ws + WS_FX + (size_t)b * 4096 + w)
                                        : (ws + WS_FY + (size_t)b * 4096 + w);
        const float* wrx  = (lane < 16) ? (wx + j * 256) : (wy + j * 256);
        float h = (lane < 16) ? bx[j] : by[j];
        #pragma unroll 8
        for (int c = 0; c < 256; ++c)
            h = fmaf(wrx[c], feat[c * 16], h);
        float mm = h;
        #pragma unroll
        for (int mk = 8; mk >= 1; mk >>= 1) mm = fmaxf(mm, __shfl_xor(mm, mk, 64));
        float ee = expf(h - mm);
        float ss = ee;
        float nn = ee * (float)w;
        #pragma unroll
        for (int mk = 8; mk >= 1; mk >>= 1) {
            ss += __shfl_xor(ss, mk, 64);
            nn += __shfl_xor(nn, mk, 64);
        }
        float cxy = nn / ss;
        if (lane == 0)  oj[0] = cxy;  // coord_x
        if (lane == 16) oj[1] = cxy;  // coord_y
    }
}

// ---------------------------------------------------------------------------
// k4: img_feat_xyz = encoding * imgz  (R2 version: nt store, 65536 blocks,
// one f4 per thread). MEASUREMENT PROBE: launched TWICE this round —
// idempotent, second launch writes identical values; dur_us delta = T(k4).
// ---------------------------------------------------------------------------
__global__ __launch_bounds__(256) void k4_bcast(const float* __restrict__ encoding,
                                                const float* __restrict__ ws,
                                                float* __restrict__ out_xyz) {
    unsigned int t = blockIdx.x * 256u + threadIdx.x;   // 0 .. 16,777,215 (float4 index)
    float e = encoding[t >> 4];                          // bc*256+hw = t/16
    const f4* imgz4 = reinterpret_cast<const f4*>(ws + WS_IMGZ);
    f4 zv = imgz4[((t >> 12) << 4) | (t & 15)];          // bc*16 + d4
    f4 r;
    r.x = e * zv.x; r.y = e * zv.y; r.z = e * zv.z; r.w = e * zv.w;
    __builtin_nontemporal_store(r, reinterpret_cast<f4*>(out_xyz) + t);
}

extern "C" void kernel_launch(void* const* d_in, const int* in_sizes, int n_in,
                              void* d_out, int out_size, void* d_ws, size_t ws_size,
                              hipStream_t stream) {
    const float* img_feat = (const float*)d_in[0];
    const float* encoding = (const float*)d_in[1];
    const float* wx   = (const float*)d_in[2];
    const float* bx   = (const float*)d_in[3];
    const float* wy   = (const float*)d_in[4];
    const float* by   = (const float*)d_in[5];
    const float* wz1  = (const float*)d_in[6];
    const float* bz1  = (const float*)d_in[7];
    const float* gamma= (const float*)d_in[8];
    const float* beta = (const float*)d_in[9];
    const float* rmean= (const float*)d_in[10];
    const float* rvar = (const float*)d_in[11];
    const float* wz2  = (const float*)d_in[12];
    const float* bz2  = (const float*)d_in[13];

    float* out = (float*)d_out;
    float* ws  = (float*)d_ws;

    k1_reduce<<<2560, 256, 0, stream>>>(img_feat, encoding, ws);
    k2_zmlp<<<4096, 256, 0, stream>>>(wz1, bz1, gamma, beta, rmean, rvar, ws);
    k3_coords<<<16 * 21, 128, 0, stream>>>(wx, bx, wy, by, wz2, bz2, ws, out);
    // PROBE: k4 twice (idempotent). dur_us - 86.2 = T(k4).
    k4_bcast<<<65536, 256, 0, stream>>>(encoding, ws, out + 1008);
    k4_bcast<<<65536, 256, 0, stream>>>(encoding, ws, out + 1008);
}

// Round 7
// 74.267 us; speedup vs baseline: 1.7324x; 1.7324x over previous
//
#include <hip/hip_runtime.h>

#define EPS 1e-5f

typedef float f4 __attribute__((ext_vector_type(4)));

// ws layout (floats):
//  fz    : [0      , 8192  )   [16][512]
//  featx : [8192   , 73728 )   [16][256][16]  (mean over H)
//  featy : [73728  , 139264)   [16][256][16]  (mean over W)
//  imgz  : [139264 , 401408)   [16][16384]    (= [16][256][64])
#define WS_FZ    0
#define WS_FX    8192
#define WS_FY    73728
#define WS_IMGZ  139264

// ---------------------------------------------------------------------------
// L1: fz only = mean(img_feat over HW). 2048 blocks (wave per (b,c)).
// ---------------------------------------------------------------------------
__global__ __launch_bounds__(256) void k1_fz(const float* __restrict__ img_feat,
                                             float* __restrict__ ws) {
    int wave = (blockIdx.x * 256 + (int)threadIdx.x) >> 6;   // 0..8191  (b*512+c)
    int lane = threadIdx.x & 63;
    const f4* src = reinterpret_cast<const f4*>(img_feat + (size_t)wave * 256);
    f4 v = src[lane];
    float s = v.x + v.y + v.z + v.w;
    #pragma unroll
    for (int m = 32; m >= 1; m >>= 1) s += __shfl_xor(s, m, 64);
    if (lane == 0) ws[WS_FZ + wave] = s * (1.0f / 256.0f);
}

// ---------------------------------------------------------------------------
// L2: blocks [0,4096): k2 z-MLP (R2-proven body).
//     blocks [4096,4608): featx/featy means (feed k3 only, hide under k2).
// ---------------------------------------------------------------------------
__global__ __launch_bounds__(256) void k2_zmlp(const float* __restrict__ wz1,
                                               const float* __restrict__ bz1,
                                               const float* __restrict__ gamma,
                                               const float* __restrict__ beta,
                                               const float* __restrict__ rmean,
                                               const float* __restrict__ rvar,
                                               const float* __restrict__ encoding,
                                               float* __restrict__ ws) {
    __shared__ float fzl[16][516];   // +4 pad: 2-way bank conflict = free
    int tid = threadIdx.x;
    int bid = blockIdx.x;

    if (bid >= 4096) {
        // featx/featy path (512 blocks)
        int t = (bid - 4096) * 256 + tid;    // 0..131071
        if (t < 65536) {
            // feat_x: t = bc*16 + w ; mean over h (stride 16)
            int w  = t & 15;
            int bc = t >> 4;
            const float* src = encoding + (size_t)bc * 256 + w;
            float s = 0.f;
            #pragma unroll
            for (int h = 0; h < 16; ++h) s += src[h * 16];
            ws[WS_FX + t] = s * (1.0f / 16.0f);
        } else {
            // feat_y: u = bc*16 + h ; mean over w (contiguous 16)
            int u  = t - 65536;
            int h  = u & 15;
            int bc = u >> 4;
            const f4* src = reinterpret_cast<const f4*>(encoding + (size_t)bc * 256 + h * 16);
            f4 a = src[0], b = src[1], c = src[2], d = src[3];
            float s = (a.x + a.y + a.z + a.w) + (b.x + b.y + b.z + b.w)
                    + (c.x + c.y + c.z + c.w) + (d.x + d.y + d.z + d.w);
            ws[WS_FY + u] = s * (1.0f / 16.0f);
        }
        return;
    }

    #pragma unroll
    for (int i = 0; i < 32; ++i) {
        int idx = i * 256 + tid;          // 0..8191
        fzl[idx >> 9][idx & 511] = ws[WS_FZ + idx];
    }
    __syncthreads();

    int o    = (bid * 256 + tid) >> 6;  // 0..16383
    int lane = tid & 63;
    int b    = lane & 15;
    int kg   = lane >> 4;               // 0..3 (128 k's each)
    const f4* wrow = reinterpret_cast<const f4*>(wz1 + (size_t)o * 512 + kg * 128);
    const f4* fr   = reinterpret_cast<const f4*>(&fzl[b][kg * 128]);
    float acc = 0.f;
    #pragma unroll
    for (int i = 0; i < 32; ++i) {
        f4 wv = wrow[i];
        f4 fv = fr[i];
        acc = fmaf(wv.x, fv.x, acc);
        acc = fmaf(wv.y, fv.y, acc);
        acc = fmaf(wv.z, fv.z, acc);
        acc = fmaf(wv.w, fv.w, acc);
    }
    acc += __shfl_xor(acc, 16, 64);
    acc += __shfl_xor(acc, 32, 64);
    if (lane < 16) {
        float z = acc + bz1[o];
        z = gamma[o] * (z - rmean[o]) * rsqrtf(rvar[o] + EPS) + beta[o];
        z = fmaxf(z, 0.f);
        ws[WS_IMGZ + (size_t)b * 16384 + o] = z;
    }
}

// ---------------------------------------------------------------------------
// L3: heterogeneous grid.
//   blocks [0,336):          k3 coords (tid<128 active; R2-proven body)
//   blocks [336,336+65536):  k4 broadcast (nt store, one f4/thread — R2-proven)
// k3 hides entirely under k4's 40 µs store stream.
// ---------------------------------------------------------------------------
__global__ __launch_bounds__(256) void k34_fused(const float* __restrict__ wx,
                                                 const float* __restrict__ bx,
                                                 const float* __restrict__ wy,
                                                 const float* __restrict__ by,
                                                 const float* __restrict__ wz2,
                                                 const float* __restrict__ bz2,
                                                 const float* __restrict__ encoding,
                                                 const float* __restrict__ ws,
                                                 float* __restrict__ out_coord,
                                                 float* __restrict__ out_xyz) {
    int bid = blockIdx.x;
    int tid = threadIdx.x;

    if (bid >= 336) {
        // ---- k4 path ----
        unsigned int t = (unsigned int)(bid - 336) * 256u + tid;  // f4 index
        float e = encoding[t >> 4];                          // bc*256+hw
        const f4* imgz4 = reinterpret_cast<const f4*>(ws + WS_IMGZ);
        f4 zv = imgz4[((t >> 12) << 4) | (t & 15)];          // bc*16 + d4
        f4 r;
        r.x = e * zv.x; r.y = e * zv.y; r.z = e * zv.z; r.w = e * zv.w;
        __builtin_nontemporal_store(r, reinterpret_cast<f4*>(out_xyz) + t);
        return;
    }

    // ---- k3 path ----
    int b = bid / 21;
    int j = bid - b * 21;
    float* oj = out_coord + (size_t)b * 63 + j * 3;

    if (tid < 64) {
        int lane = tid;
        const float* imgz = ws + WS_IMGZ + (size_t)b * 16384;
        const float* wr   = wz2 + j * 256;
        float hz = bz2[j];
        #pragma unroll 8
        for (int c = 0; c < 256; ++c)
            hz = fmaf(wr[c], imgz[c * 64 + lane], hz);

        float m = hz;
        #pragma unroll
        for (int mk = 32; mk >= 1; mk >>= 1) m = fmaxf(m, __shfl_xor(m, mk, 64));
        float e = expf(hz - m);
        float s = e;
        float n = e * (float)lane;
        #pragma unroll
        for (int mk = 32; mk >= 1; mk >>= 1) {
            s += __shfl_xor(s, mk, 64);
            n += __shfl_xor(n, mk, 64);
        }
        if (lane == 0) oj[2] = n / s;
    } else if (tid < 96) {
        int lane = tid - 64;
        int w = lane & 15;
        const float* feat = (lane < 16) ? (ws + WS_FX + (size_t)b * 4096 + w)
                                        : (ws + WS_FY + (size_t)b * 4096 + w);
        const float* wrx  = (lane < 16) ? (wx + j * 256) : (wy + j * 256);
        float h = (lane < 16) ? bx[j] : by[j];
        #pragma unroll 8
        for (int c = 0; c < 256; ++c)
            h = fmaf(wrx[c], feat[c * 16], h);
        float mm = h;
        #pragma unroll
        for (int mk = 8; mk >= 1; mk >>= 1) mm = fmaxf(mm, __shfl_xor(mm, mk, 64));
        float ee = expf(h - mm);
        float ss = ee;
        float nn = ee * (float)w;
        #pragma unroll
        for (int mk = 8; mk >= 1; mk >>= 1) {
            ss += __shfl_xor(ss, mk, 64);
            nn += __shfl_xor(nn, mk, 64);
        }
        float cxy = nn / ss;
        if (lane == 0)  oj[0] = cxy;  // coord_x
        if (lane == 16) oj[1] = cxy;  // coord_y
    }
}

extern "C" void kernel_launch(void* const* d_in, const int* in_sizes, int n_in,
                              void* d_out, int out_size, void* d_ws, size_t ws_size,
                              hipStream_t stream) {
    const float* img_feat = (const float*)d_in[0];
    const float* encoding = (const float*)d_in[1];
    const float* wx   = (const float*)d_in[2];
    const float* bx   = (const float*)d_in[3];
    const float* wy   = (const float*)d_in[4];
    const float* by   = (const float*)d_in[5];
    const float* wz1  = (const float*)d_in[6];
    const float* bz1  = (const float*)d_in[7];
    const float* gamma= (const float*)d_in[8];
    const float* beta = (const float*)d_in[9];
    const float* rmean= (const float*)d_in[10];
    const float* rvar = (const float*)d_in[11];
    const float* wz2  = (const float*)d_in[12];
    const float* bz2  = (const float*)d_in[13];

    float* out = (float*)d_out;
    float* ws  = (float*)d_ws;

    // L1: fz only (2048 blocks)
    k1_fz<<<2048, 256, 0, stream>>>(img_feat, ws);
    // L2: k2 (4096) + featx/featy (512)
    k2_zmlp<<<4608, 256, 0, stream>>>(wz1, bz1, gamma, beta, rmean, rvar,
                                      encoding, ws);
    // L3: k3 (336) + k4 (65536)
    k34_fused<<<336 + 65536, 256, 0, stream>>>(wx, bx, wy, by, wz2, bz2,
                                               encoding, ws, out, out + 1008);
}